// Round 3
// baseline (766.590 us; speedup 1.0000x reference)
//
#include <hip/hip_runtime.h>

#define VOCABSZ 256
#define EMBED   32
#define HIDDEN  32
#define LAYERS  10
#define BATCH   1024
#define SEQ     1024
#define BPB     16      // batch elems per block (= MFMA N)
#define PITCH   80      // bytes per h row in LDS (64B payload + 16B pad)

typedef _Float16 f16x8 __attribute__((ext_vector_type(8)));
typedef float    f32x4 __attribute__((ext_vector_type(4)));
typedef _Float16 h2    __attribute__((ext_vector_type(2)));

__device__ __forceinline__ unsigned pk(float a, float b) {
    h2 t; t[0] = (_Float16)a; t[1] = (_Float16)b;
    return __builtin_bit_cast(unsigned, t);
}
__device__ __forceinline__ f16x8 u2f(uint4 u) { return __builtin_bit_cast(f16x8, u); }

// One block = 16 batch elems, 640 threads = 10 waves, wave w owns layer w.
// Per iter per wave: D[32h x 16b] = Wcat[32x64] @ Xcat^T[64x16] via 4 MFMA
// (2 M-tiles x 2 K-steps), then bias+tanh on 8 f32/lane, pack f16, 2 b64
// LDS writes. Handoff layout [batch][hidden] f16 rows (PITCH=80) makes the
// next layer's B-fragment a single ds_read_b128 at [lane&15][(lane>>4)*16B].
__global__ __launch_bounds__(640, 1) void rnn_mfma(
    const int* __restrict__ x, const float* __restrict__ emb,
    const float* __restrict__ W_ih, const float* __restrict__ W_hh,
    const float* __restrict__ b_ih, const float* __restrict__ b_hh,
    float* __restrict__ h_out)
{
    __shared__ unsigned xl[(SEQ / 4) * BPB];                         // 16 KB tokens, [t/4][b], 4 tok/u32
    __shared__ __align__(16) unsigned char hl[2 * LAYERS * BPB * PITCH]; // 25.6 KB h double-buffer

    const int tid   = threadIdx.x;
    const int w     = tid >> 6;       // wave == layer
    const int lane  = tid & 63;
    const int bc    = lane & 15;      // batch col (B/C col) == A row-in-tile
    const int g     = lane >> 4;      // k-group / C row-group
    const int bbase = blockIdx.x * BPB;

    // ---- stage tokens: block's 16 rows are contiguous in x; pack 4 tok/u32, layout [t/4][b]
    const int4* xg4 = (const int4*)(x + bbase * SEQ);
    for (int i = tid; i < (SEQ / 4) * BPB; i += 640) {
        const int4 v = xg4[i];
        xl[(i & 255) * BPB + (i >> 8)] =
            (unsigned)(v.x | (v.y << 8) | (v.z << 16) | (v.w << 24));
    }
    // ---- zero h (h0 = 0; covers both parities and the pads)
    for (int i = tid; i < (2 * LAYERS * BPB * PITCH) / 4; i += 640)
        ((unsigned*)hl)[i] = 0u;

    // ---- weight A-fragments: wf[mt][ks] = Wsrc[16*mt + bc][8g .. 8g+7], f16
    f16x8 wf00, wf01, wf10, wf11;
    {
        const float4* p00 = (const float4*)(W_ih + (w * HIDDEN + bc)      * EMBED  + g * 8);
        const float4* p10 = (const float4*)(W_ih + (w * HIDDEN + 16 + bc) * EMBED  + g * 8);
        const float4* p01 = (const float4*)(W_hh + (w * HIDDEN + bc)      * HIDDEN + g * 8);
        const float4* p11 = (const float4*)(W_hh + (w * HIDDEN + 16 + bc) * HIDDEN + g * 8);
        float4 a, b;
        a = p00[0]; b = p00[1];
        wf00 = u2f(uint4{pk(a.x, a.y), pk(a.z, a.w), pk(b.x, b.y), pk(b.z, b.w)});
        a = p01[0]; b = p01[1];
        wf01 = u2f(uint4{pk(a.x, a.y), pk(a.z, a.w), pk(b.x, b.y), pk(b.z, b.w)});
        a = p10[0]; b = p10[1];
        wf10 = u2f(uint4{pk(a.x, a.y), pk(a.z, a.w), pk(b.x, b.y), pk(b.z, b.w)});
        a = p11[0]; b = p11[1];
        wf11 = u2f(uint4{pk(a.x, a.y), pk(a.z, a.w), pk(b.x, b.y), pk(b.z, b.w)});
    }
    // ---- bias per C element: hidden = 16*mt + 4*g + r
    float bias[8];
    #pragma unroll
    for (int m = 0; m < 2; ++m)
        #pragma unroll
        for (int r = 0; r < 4; ++r) {
            const int hid = w * HIDDEN + m * 16 + g * 4 + r;
            bias[m * 4 + r] = b_ih[hid] + b_hh[hid];
        }

    // ---- precomputed LDS byte offsets (parity-static; selected by literal WP)
    #define HB(p, s, b) ((((p) * LAYERS + (s)) * BPB + (b)) * PITCH)
    const int rin0  = (w > 0) ? HB(0, w - 1, bc) + 16 * g : 0;
    const int rin1  = (w > 0) ? HB(1, w - 1, bc) + 16 * g : 0;
    const int rown0 = HB(0, w, bc) + 16 * g;
    const int rown1 = HB(1, w, bc) + 16 * g;
    const int wr0   = HB(0, w, bc) + 8 * g;
    const int wr1   = HB(1, w, bc) + 8 * g;

    // ---- embedding B-fragment gather (wave 0 only): col=bc=batch, k=8g..8g+7
    auto gather = [&](int tt) -> uint4 {
        const unsigned gw = xl[(tt >> 2) * BPB + bc];
        const int tok = (gw >> ((tt & 3) * 8)) & 255;
        const float4* ep = (const float4*)(emb + tok * EMBED + g * 8);
        const float4 e0 = ep[0], e1 = ep[1];
        return uint4{pk(e0.x, e0.y), pk(e0.z, e0.w), pk(e1.x, e1.y), pk(e1.z, e1.w)};
    };

    __syncthreads();  // xl + hl zero-init visible

    uint4 eA{0, 0, 0, 0}, eB{0, 0, 0, 0};
    if (w == 0) { eA = gather(0); eB = gather(1); }   // t=0 (even->eA), t=1 (odd->eB)

    auto body = [&](int IT, int WP) {
        __syncthreads();                 // single per-step barrier (RAW+WAR)
        const int t = IT - w;
        if (t >= 0 && t < SEQ) {         // wave-uniform
            // read parity = WP^1
            const uint4 bown = *(const uint4*)(hl + (WP ? rown0 : rown1));
            uint4 bin;
            if (w == 0) bin = WP ? eB : eA;
            else        bin = *(const uint4*)(hl + (WP ? rin0 : rin1));

            f32x4 c0 = {0.f, 0.f, 0.f, 0.f}, c1 = {0.f, 0.f, 0.f, 0.f};
            c0 = __builtin_amdgcn_mfma_f32_16x16x32_f16(wf00, u2f(bin),  c0, 0, 0, 0);
            c1 = __builtin_amdgcn_mfma_f32_16x16x32_f16(wf10, u2f(bin),  c1, 0, 0, 0);
            c0 = __builtin_amdgcn_mfma_f32_16x16x32_f16(wf01, u2f(bown), c0, 0, 0, 0);
            c1 = __builtin_amdgcn_mfma_f32_16x16x32_f16(wf11, u2f(bown), c1, 0, 0, 0);

            float hv[8];
            #pragma unroll
            for (int r = 0; r < 4; ++r) {
                {
                    const float a  = c0[r] + bias[r];
                    const float e  = __expf(a + a);
                    const float rc = __builtin_amdgcn_rcpf(1.0f + e);
                    hv[r] = 1.0f - (rc + rc);            // tanh
                }
                {
                    const float a  = c1[r] + bias[4 + r];
                    const float e  = __expf(a + a);
                    const float rc = __builtin_amdgcn_rcpf(1.0f + e);
                    hv[4 + r] = 1.0f - (rc + rc);
                }
            }

            // write parity = WP: [batch bc][hidden 4g..4g+3] and [.. 16+4g..]
            const int wb = WP ? wr1 : wr0;
            *(uint2*)(hl + wb)      = uint2{pk(hv[0], hv[1]), pk(hv[2], hv[3])};
            *(uint2*)(hl + wb + 32) = uint2{pk(hv[4], hv[5]), pk(hv[6], hv[7])};

            // feeder: refill the fragment consumed this parity with t+2
            if (w == 0 && t + 2 < SEQ) {
                if (WP) eB = gather(t + 2); else eA = gather(t + 2);
            }
            // drain: final hidden of top layer, f32 (pre-f16-rounding)
            if (w == LAYERS - 1 && t == SEQ - 1) {
                #pragma unroll
                for (int r = 0; r < 4; ++r) {
                    h_out[(bbase + bc) * HIDDEN + g * 4 + r]      = hv[r];
                    h_out[(bbase + bc) * HIDDEN + 16 + g * 4 + r] = hv[4 + r];
                }
            }
        }
    };

    for (int it = 0; it < SEQ + LAYERS; it += 2) {  // 1034 steps, parity static
        body(it, 0);
        body(it + 1, 1);
    }
}

// Epilogue: out[b][v] = h_fin[b][:] . W_fc[v][:] + b_fc[v]  (fp32)
__global__ __launch_bounds__(256) void rnn_fc(
    const float* __restrict__ h_fin, const float* __restrict__ W_fc,
    const float* __restrict__ b_fc, float* __restrict__ out)
{
    const int b = blockIdx.x;
    const int v = threadIdx.x;
    const float4* hr = (const float4*)(h_fin + b * HIDDEN);
    const float4* wr = (const float4*)(W_fc + v * HIDDEN);
    float acc = b_fc[v];
    #pragma unroll
    for (int c = 0; c < 8; ++c) {
        const float4 hv = hr[c], wv = wr[c];
        acc += hv.x * wv.x + hv.y * wv.y + hv.z * wv.z + hv.w * wv.w;
    }
    out[b * VOCABSZ + v] = acc;
}

extern "C" void kernel_launch(void* const* d_in, const int* in_sizes, int n_in,
                              void* d_out, int out_size, void* d_ws, size_t ws_size,
                              hipStream_t stream) {
    const int*   x    = (const int*)d_in[0];
    const float* emb  = (const float*)d_in[1];
    const float* W_ih = (const float*)d_in[2];
    const float* W_hh = (const float*)d_in[3];
    const float* b_ih = (const float*)d_in[4];
    const float* b_hh = (const float*)d_in[5];
    const float* W_fc = (const float*)d_in[6];
    const float* b_fc = (const float*)d_in[7];
    float* out   = (float*)d_out;
    float* h_fin = (float*)d_ws;    // BATCH*HIDDEN f32 = 128 KB scratch

    rnn_mfma<<<BATCH / BPB, 640, 0, stream>>>(x, emb, W_ih, W_hh, b_ih, b_hh, h_fin);
    rnn_fc<<<BATCH, VOCABSZ, 0, stream>>>(h_fin, W_fc, b_fc, out);
}

// Round 4
// 617.067 us; speedup vs baseline: 1.2423x; 1.2423x over previous
//
#include <hip/hip_runtime.h>

#define VOCABSZ 256
#define EMBED   32
#define HIDDEN  32
#define LAYERS  10
#define BATCH   1024
#define SEQ     1024
#define BPB     16      // batch elems per block (= MFMA N)
#define U       4       // timesteps per wave per barrier interval
#define NITER   (SEQ / U + LAYERS - 1)   // 265

typedef _Float16 f16x8 __attribute__((ext_vector_type(8)));
typedef float    f32x4 __attribute__((ext_vector_type(4)));
typedef _Float16 h2    __attribute__((ext_vector_type(2)));

__device__ __forceinline__ unsigned pk(float a, float b) {
    h2 t; t[0] = (_Float16)a; t[1] = (_Float16)b;
    return __builtin_bit_cast(unsigned, t);
}
__device__ __forceinline__ f16x8 u2f(uint4 u) { return __builtin_bit_cast(f16x8, u); }

// Persistent skewed layer-pipeline, U=4 timesteps per barrier.
// Block = 16 batch elems, 640 thr = 10 waves, wave w owns layer w.
// h handoff in k-major LDS layout [kword][bc][16B] (1 KB per h-vector set):
//   B-frag read:  16B @ g*256 + bc*16                  (2-way, ~free)
//   C-frag write: 8B  @ (g>>1)*256 + bc*16 + 8*(g&1)   (2-way, ~free)
// (round-3 layout had 4-way write conflicts = 334 cy/iter: the fix)
__global__ __launch_bounds__(640, 1) void rnn_mfma(
    const int* __restrict__ x, const float* __restrict__ emb,
    const float* __restrict__ W_ih, const float* __restrict__ W_hh,
    const float* __restrict__ b_ih, const float* __restrict__ b_hh,
    float* __restrict__ h_out)
{
    __shared__ unsigned xl[(SEQ / 4) * BPB];                      // 16 KB tokens [t/4][b]
    __shared__ __align__(16) unsigned char hb[2 * LAYERS * U * 1024]; // 80 KB h slots

    const int tid   = threadIdx.x;
    const int w     = tid >> 6;       // wave == layer
    const int lane  = tid & 63;
    const int bc    = lane & 15;      // batch col
    const int g     = lane >> 4;      // k-group / C row-group
    const int bbase = blockIdx.x * BPB;

    // ---- stage tokens: pack 4 consecutive t per u32, layout [t/4][b]
    const int4* xg4 = (const int4*)(x + bbase * SEQ);
    for (int i = tid; i < (SEQ / 4) * BPB; i += 640) {
        const int4 v = xg4[i];
        xl[(i & 255) * BPB + (i >> 8)] =
            (unsigned)(v.x | (v.y << 8) | (v.z << 16) | (v.w << 24));
    }
    // ---- zero h slots (h0 = 0)
    for (int i = tid; i < (int)sizeof(hb) / 4; i += 640)
        ((unsigned*)hb)[i] = 0u;

    // ---- weight A-fragments (identical construction to validated round 3)
    f16x8 wf00, wf01, wf10, wf11;
    {
        const float4* p00 = (const float4*)(W_ih + (w * HIDDEN + bc)      * EMBED  + g * 8);
        const float4* p10 = (const float4*)(W_ih + (w * HIDDEN + 16 + bc) * EMBED  + g * 8);
        const float4* p01 = (const float4*)(W_hh + (w * HIDDEN + bc)      * HIDDEN + g * 8);
        const float4* p11 = (const float4*)(W_hh + (w * HIDDEN + 16 + bc) * HIDDEN + g * 8);
        float4 a, b;
        a = p00[0]; b = p00[1];
        wf00 = u2f(uint4{pk(a.x, a.y), pk(a.z, a.w), pk(b.x, b.y), pk(b.z, b.w)});
        a = p01[0]; b = p01[1];
        wf01 = u2f(uint4{pk(a.x, a.y), pk(a.z, a.w), pk(b.x, b.y), pk(b.z, b.w)});
        a = p10[0]; b = p10[1];
        wf10 = u2f(uint4{pk(a.x, a.y), pk(a.z, a.w), pk(b.x, b.y), pk(b.z, b.w)});
        a = p11[0]; b = p11[1];
        wf11 = u2f(uint4{pk(a.x, a.y), pk(a.z, a.w), pk(b.x, b.y), pk(b.z, b.w)});
    }
    float bias[8];
    #pragma unroll
    for (int m = 0; m < 2; ++m)
        #pragma unroll
        for (int r = 0; r < 4; ++r) {
            const int hid = w * HIDDEN + m * 16 + g * 4 + r;
            bias[m * 4 + r] = b_ih[hid] + b_hh[hid];
        }

    // slot byte base: (parity, layer, u)
    #define SL(p, l, u) ((((p) * LAYERS + (l)) * U + (u)) * 1024)
    const int rd_off  = g * 256 + bc * 16;                    // B-frag read
    const int wr_off0 = (g >> 1) * 256 + bc * 16 + (g & 1) * 8; // C rows 4g..4g+3
    const int wr_off1 = wr_off0 + 512;                          // C rows 16+4g..

    __syncthreads();  // xl + hb-zero visible

    // ---- wave-0 feeder state: cur = frags for this iter, eraw = raw rows for next
    uint4  cur[U];
    float4 eraw[U][2];
    if (w == 0) {
        const unsigned gw = xl[0 * BPB + bc];    // tokens t=0..3 of batch bc
        #pragma unroll
        for (int u = 0; u < U; ++u) {
            const int tok = (gw >> (8 * u)) & 255;
            const float4* ep = (const float4*)(emb + tok * EMBED + g * 8);
            const float4 e0 = ep[0], e1 = ep[1];
            cur[u] = uint4{pk(e0.x, e0.y), pk(e0.z, e0.w), pk(e1.x, e1.y), pk(e1.z, e1.w)};
        }
    }

    auto body = [&](int it, int P) {
        __syncthreads();                       // one barrier per U timesteps
        const int tb = (it - w) * U;
        if (tb < 0 || tb >= SEQ) return;       // wave-uniform

        // feeder: issue next-iter embedding loads now; pack at iter end
        const bool pf = (w == 0) && (tb + U < SEQ);
        if (pf) {
            const unsigned gw = xl[((tb + U) >> 2) * BPB + bc];
            #pragma unroll
            for (int u = 0; u < U; ++u) {
                const int tok = (gw >> (8 * u)) & 255;
                const float4* ep = (const float4*)(emb + tok * EMBED + g * 8);
                eraw[u][0] = ep[0]; eraw[u][1] = ep[1];
            }
        }

        // all U input frags + initial own-h up front (off the serial chain)
        uint4 bin[U];
        if (w == 0) {
            #pragma unroll
            for (int u = 0; u < U; ++u) bin[u] = cur[u];
        } else {
            #pragma unroll
            for (int u = 0; u < U; ++u)
                bin[u] = *(const uint4*)(hb + SL(P ^ 1, w - 1, u) + rd_off);
        }
        uint4 bown = *(const uint4*)(hb + SL(P ^ 1, w, U - 1) + rd_off);

        #pragma unroll
        for (int u = 0; u < U; ++u) {
            f32x4 c0 = {0.f, 0.f, 0.f, 0.f}, c1 = {0.f, 0.f, 0.f, 0.f};
            c0 = __builtin_amdgcn_mfma_f32_16x16x32_f16(wf00, u2f(bin[u]), c0, 0, 0, 0);
            c1 = __builtin_amdgcn_mfma_f32_16x16x32_f16(wf10, u2f(bin[u]), c1, 0, 0, 0);
            c0 = __builtin_amdgcn_mfma_f32_16x16x32_f16(wf01, u2f(bown),   c0, 0, 0, 0);
            c1 = __builtin_amdgcn_mfma_f32_16x16x32_f16(wf11, u2f(bown),   c1, 0, 0, 0);

            float hv[8];
            #pragma unroll
            for (int r = 0; r < 4; ++r) {
                {
                    const float a  = c0[r] + bias[r];
                    const float e  = __expf(a + a);
                    const float rc = __builtin_amdgcn_rcpf(1.0f + e);
                    hv[r] = 1.0f - (rc + rc);               // tanh
                }
                {
                    const float a  = c1[r] + bias[4 + r];
                    const float e  = __expf(a + a);
                    const float rc = __builtin_amdgcn_rcpf(1.0f + e);
                    hv[4 + r] = 1.0f - (rc + rc);
                }
            }

            const int sb = SL(P, w, u);
            *(uint2*)(hb + sb + wr_off0) = uint2{pk(hv[0], hv[1]), pk(hv[2], hv[3])};
            *(uint2*)(hb + sb + wr_off1) = uint2{pk(hv[4], hv[5]), pk(hv[6], hv[7])};

            if (u < U - 1)   // own-h for next timestep (wave-local lgkmcnt, no barrier)
                bown = *(const uint4*)(hb + sb + rd_off);

            if (w == LAYERS - 1 && tb + u == SEQ - 1) {
                #pragma unroll
                for (int r = 0; r < 4; ++r) {
                    h_out[(bbase + bc) * HIDDEN + g * 4 + r]      = hv[r];
                    h_out[(bbase + bc) * HIDDEN + 16 + g * 4 + r] = hv[4 + r];
                }
            }
        }

        if (pf) {   // pack next-iter frags (global-load latency spanned the iter)
            #pragma unroll
            for (int u = 0; u < U; ++u) {
                const float4 e0 = eraw[u][0], e1 = eraw[u][1];
                cur[u] = uint4{pk(e0.x, e0.y), pk(e0.z, e0.w), pk(e1.x, e1.y), pk(e1.z, e1.w)};
            }
        }
    };

    for (int it = 0; it < NITER + 1; it += 2) {  // parity static per body
        body(it, 0);
        body(it + 1, 1);
    }
    #undef SL
}

// Epilogue: out[b][v] = h_fin[b][:] . W_fc[v][:] + b_fc[v]  (fp32)
__global__ __launch_bounds__(256) void rnn_fc(
    const float* __restrict__ h_fin, const float* __restrict__ W_fc,
    const float* __restrict__ b_fc, float* __restrict__ out)
{
    const int b = blockIdx.x;
    const int v = threadIdx.x;
    const float4* hr = (const float4*)(h_fin + b * HIDDEN);
    const float4* wr = (const float4*)(W_fc + v * HIDDEN);
    float acc = b_fc[v];
    #pragma unroll
    for (int c = 0; c < 8; ++c) {
        const float4 hv = hr[c], wv = wr[c];
        acc += hv.x * wv.x + hv.y * wv.y + hv.z * wv.z + hv.w * wv.w;
    }
    out[b * VOCABSZ + v] = acc;
}

extern "C" void kernel_launch(void* const* d_in, const int* in_sizes, int n_in,
                              void* d_out, int out_size, void* d_ws, size_t ws_size,
                              hipStream_t stream) {
    const int*   x    = (const int*)d_in[0];
    const float* emb  = (const float*)d_in[1];
    const float* W_ih = (const float*)d_in[2];
    const float* W_hh = (const float*)d_in[3];
    const float* b_ih = (const float*)d_in[4];
    const float* b_hh = (const float*)d_in[5];
    const float* W_fc = (const float*)d_in[6];
    const float* b_fc = (const float*)d_in[7];
    float* out   = (float*)d_out;
    float* h_fin = (float*)d_ws;    // BATCH*HIDDEN f32 = 128 KB scratch

    rnn_mfma<<<BATCH / BPB, 640, 0, stream>>>(x, emb, W_ih, W_hh, b_ih, b_hh, h_fin);
    rnn_fc<<<BATCH, VOCABSZ, 0, stream>>>(h_fin, W_fc, b_fc, out);
}

// Round 6
// 535.048 us; speedup vs baseline: 1.4328x; 1.1533x over previous
//
#include <hip/hip_runtime.h>

#define VOCABSZ 256
#define EMBED   32
#define HIDDEN  32
#define LAYERS  10
#define BATCH   1024
#define SEQ     1024
#define BPB     16      // batch elems per block (= MFMA N)
#define U       4       // timesteps per wave per barrier interval
#define NITER   (SEQ / U + LAYERS - 1)   // 265

typedef _Float16 f16x8 __attribute__((ext_vector_type(8)));
typedef float    f32x4 __attribute__((ext_vector_type(4)));
typedef _Float16 h2    __attribute__((ext_vector_type(2)));

__device__ __forceinline__ unsigned pk(float a, float b) {
    h2 t; t[0] = (_Float16)a; t[1] = (_Float16)b;
    return __builtin_bit_cast(unsigned, t);
}
__device__ __forceinline__ f16x8 u2f(uint4 u) { return __builtin_bit_cast(f16x8, u); }

// tanh(c + bias) with bias prefolded: t = c*2log2e + bias2; 1 - 2/(1+2^t).
// Saturates correctly at +/-inf. 3 VALU + 2 TRANS.
__device__ __forceinline__ float th(float c, float b2) {
    const float t = __builtin_fmaf(c, 2.8853900817779268f, b2);
#if __has_builtin(__builtin_amdgcn_exp2f)
    const float e = __builtin_amdgcn_exp2f(t);
#else
    const float e = __expf(0.6931471805599453f * t);
#endif
    const float r = __builtin_amdgcn_rcpf(1.0f + e);
    return __builtin_fmaf(-2.0f, r, 1.0f);
}

// A-fragment builders: lane (bc,g) takes 8 cols of its weight row, f16-packed.
// natural: cols 8g..8g+7.  kperm: cols {4g..4g+3, 16+4g..16+4g+3} (the kappa
// permutation that makes C-fragment outputs land in-lane as the next B-frag).
__device__ __forceinline__ uint4 mk_nat(const float* row, int g) {
    const float4 a = *(const float4*)(row + 8 * g);
    const float4 b = *(const float4*)(row + 8 * g + 4);
    return uint4{pk(a.x, a.y), pk(a.z, a.w), pk(b.x, b.y), pk(b.z, b.w)};
}
__device__ __forceinline__ uint4 mk_kp(const float* row, int g) {
    const float4 a = *(const float4*)(row + 4 * g);
    const float4 b = *(const float4*)(row + 16 + 4 * g);
    return uint4{pk(a.x, a.y), pk(a.z, a.w), pk(b.x, b.y), pk(b.z, b.w)};
}

// Persistent skewed layer-pipeline. Block = 16 batch, 640 thr = 10 waves,
// wave w owns layer w. kappa-permuted weight columns make the recurrence
// fully in-register: mfma -> tanh -> pack IS the next B-fragment (no LDS,
// no cross-lane). Cross-layer handoff: one ds_write_b128 / ds_read_b128.
// ROUND-6 FIX: token loads were missing the per-block batch offset bbase
// (every block consumed block-0's tokens -> absmax 4.5e-2).
__global__ __launch_bounds__(640, 1) void rnn_mfma(
    const int* __restrict__ x, const float* __restrict__ emb,
    const float* __restrict__ W_ih, const float* __restrict__ W_hh,
    const float* __restrict__ b_ih, const float* __restrict__ b_hh,
    float* __restrict__ h_out)
{
    __shared__ __align__(16) unsigned char hb[2 * LAYERS * U * 1024]; // 80 KB

    const int tid   = threadIdx.x;
    const int w     = tid >> 6;       // wave == layer
    const int lane  = tid & 63;
    const int bc    = lane & 15;      // batch col
    const int g     = lane >> 4;      // k-group / C row-group
    const int bbase = blockIdx.x * BPB;

    // zero h slots (h0 = 0); conflict-free stride loop
    for (int i = tid; i < (int)sizeof(hb) / 4; i += 640)
        ((unsigned*)hb)[i] = 0u;

    // ---- weight A-fragments (kappa-permuted cols; layer-0 W_ih natural)
    const float* ri0 = W_ih + (w * HIDDEN + bc)      * EMBED;
    const float* ri1 = W_ih + (w * HIDDEN + 16 + bc) * EMBED;
    const float* rh0 = W_hh + (w * HIDDEN + bc)      * HIDDEN;
    const float* rh1 = W_hh + (w * HIDDEN + 16 + bc) * HIDDEN;
    const uint4 wf00 = (w == 0) ? mk_nat(ri0, g) : mk_kp(ri0, g);
    const uint4 wf10 = (w == 0) ? mk_nat(ri1, g) : mk_kp(ri1, g);
    const uint4 wf01 = mk_kp(rh0, g);
    const uint4 wf11 = mk_kp(rh1, g);

    // bias prefolded with the exp2 scale: bias2 = 2log2e * (b_ih + b_hh)
    float bias2[8];
    #pragma unroll
    for (int m = 0; m < 2; ++m)
        #pragma unroll
        for (int r = 0; r < 4; ++r) {
            const int hid = w * HIDDEN + m * 16 + g * 4 + r;
            bias2[m * 4 + r] = 2.8853900817779268f * (b_ih[hid] + b_hh[hid]);
        }

    #define SL(p, l, u) ((((p) * LAYERS + (l)) * U + (u)) * 1024)
    const int off = g * 256 + bc * 16;   // b128 frag address (write == read image)

    // ---- wave-0 feeder: cur = input frags for this iter; 2-level prefetch
    uint4  cur[U];
    float4 eraw[U][2];
    int4   tok_pf;
    if (w == 0) {
        const int4 t4 = *(const int4*)(x + (bbase + bc) * SEQ);   // tokens t=0..3
        const int tk[U] = {t4.x, t4.y, t4.z, t4.w};
        #pragma unroll
        for (int u = 0; u < U; ++u) {
            const float4* ep = (const float4*)(emb + tk[u] * EMBED + g * 8);
            const float4 e0 = ep[0], e1 = ep[1];
            cur[u] = uint4{pk(e0.x, e0.y), pk(e0.z, e0.w), pk(e1.x, e1.y), pk(e1.z, e1.w)};
        }
        tok_pf = *(const int4*)(x + (bbase + bc) * SEQ + U);      // tokens t=4..7
    }

    uint4 bown = uint4{0, 0, 0, 0};   // own-h B-frag, lives in registers forever

    auto body = [&](int it, int P) {
        __syncthreads();                       // one barrier per U timesteps
        const int tb = (it - w) * U;
        if (tb < 0 || tb >= SEQ) return;       // wave-uniform

        // feeder: issue next-iter emb gathers (tokens prefetched last iter)
        const bool pf = (w == 0) && (tb + U < SEQ);
        if (pf) {
            const int tk[U] = {tok_pf.x, tok_pf.y, tok_pf.z, tok_pf.w};
            #pragma unroll
            for (int u = 0; u < U; ++u) {
                const float4* ep = (const float4*)(emb + tk[u] * EMBED + g * 8);
                eraw[u][0] = ep[0]; eraw[u][1] = ep[1];
            }
            if (tb + 2 * U < SEQ)
                tok_pf = *(const int4*)(x + (bbase + bc) * SEQ + tb + 2 * U);
        }

        // input fragments + batched input MFMAs (off the serial chain)
        uint4 bin[U];
        if (w == 0) {
            #pragma unroll
            for (int u = 0; u < U; ++u) bin[u] = cur[u];
        } else {
            #pragma unroll
            for (int u = 0; u < U; ++u)
                bin[u] = *(const uint4*)(hb + SL(P ^ 1, w - 1, u) + off);
        }
        f32x4 cin0[U], cin1[U];
        const f32x4 z = {0.f, 0.f, 0.f, 0.f};
        #pragma unroll
        for (int u = 0; u < U; ++u) {
            cin0[u] = __builtin_amdgcn_mfma_f32_16x16x32_f16(u2f(wf00), u2f(bin[u]), z, 0, 0, 0);
            cin1[u] = __builtin_amdgcn_mfma_f32_16x16x32_f16(u2f(wf10), u2f(bin[u]), z, 0, 0, 0);
        }

        // serial recurrence: mfma -> tanh -> pack IS the next B-frag (in-lane)
        #pragma unroll
        for (int u = 0; u < U; ++u) {
            const f32x4 c0 = __builtin_amdgcn_mfma_f32_16x16x32_f16(u2f(wf01), u2f(bown), cin0[u], 0, 0, 0);
            const f32x4 c1 = __builtin_amdgcn_mfma_f32_16x16x32_f16(u2f(wf11), u2f(bown), cin1[u], 0, 0, 0);

            float hv[8];
            #pragma unroll
            for (int r = 0; r < 4; ++r) {
                hv[r]     = th(c0[r], bias2[r]);
                hv[4 + r] = th(c1[r], bias2[4 + r]);
            }
            bown = uint4{pk(hv[0], hv[1]), pk(hv[2], hv[3]),
                         pk(hv[4], hv[5]), pk(hv[6], hv[7])};

            if (w < LAYERS - 1)   // handoff for next layer (one b128)
                *(uint4*)(hb + SL(P, w, u) + off) = bown;

            if (w == LAYERS - 1 && tb + u == SEQ - 1) {
                #pragma unroll
                for (int r = 0; r < 4; ++r) {
                    h_out[(bbase + bc) * HIDDEN + g * 4 + r]      = hv[r];
                    h_out[(bbase + bc) * HIDDEN + 16 + g * 4 + r] = hv[4 + r];
                }
            }
        }

        if (pf) {   // pack next-iter input frags (emb loads spanned the iter)
            #pragma unroll
            for (int u = 0; u < U; ++u) {
                const float4 e0 = eraw[u][0], e1 = eraw[u][1];
                cur[u] = uint4{pk(e0.x, e0.y), pk(e0.z, e0.w), pk(e1.x, e1.y), pk(e1.z, e1.w)};
            }
        }
    };

    for (int it = 0; it < NITER + 1; it += 2) {  // parity static per body
        body(it, 0);
        body(it + 1, 1);
    }
    #undef SL
}

// Epilogue: out[b][v] = h_fin[b][:] . W_fc[v][:] + b_fc[v]  (fp32)
__global__ __launch_bounds__(256) void rnn_fc(
    const float* __restrict__ h_fin, const float* __restrict__ W_fc,
    const float* __restrict__ b_fc, float* __restrict__ out)
{
    const int b = blockIdx.x;
    const int v = threadIdx.x;
    const float4* hr = (const float4*)(h_fin + b * HIDDEN);
    const float4* wr = (const float4*)(W_fc + v * HIDDEN);
    float acc = b_fc[v];
    #pragma unroll
    for (int c = 0; c < 8; ++c) {
        const float4 hv = hr[c], wv = wr[c];
        acc += hv.x * wv.x + hv.y * wv.y + hv.z * wv.z + hv.w * wv.w;
    }
    out[b * VOCABSZ + v] = acc;
}

extern "C" void kernel_launch(void* const* d_in, const int* in_sizes, int n_in,
                              void* d_out, int out_size, void* d_ws, size_t ws_size,
                              hipStream_t stream) {
    const int*   x    = (const int*)d_in[0];
    const float* emb  = (const float*)d_in[1];
    const float* W_ih = (const float*)d_in[2];
    const float* W_hh = (const float*)d_in[3];
    const float* b_ih = (const float*)d_in[4];
    const float* b_hh = (const float*)d_in[5];
    const float* W_fc = (const float*)d_in[6];
    const float* b_fc = (const float*)d_in[7];
    float* out   = (float*)d_out;
    float* h_fin = (float*)d_ws;    // BATCH*HIDDEN f32 = 128 KB scratch

    rnn_mfma<<<BATCH / BPB, 640, 0, stream>>>(x, emb, W_ih, W_hh, b_ih, b_hh, h_fin);
    rnn_fc<<<BATCH, VOCABSZ, 0, stream>>>(h_fin, W_fc, b_fc, out);
}